// Round 13
// baseline (1349.911 us; speedup 1.0000x reference)
//
#include <hip/hip_runtime.h>
#include <stdint.h>

// B=32, T=128, DIN=DOUT=1024. Input dtypes detected at runtime (bf16 vs fp32).
typedef unsigned short u16;
typedef unsigned long long u64;
typedef __attribute__((ext_vector_type(8))) short short8;   // 8 x bf16 MFMA operand
typedef __attribute__((ext_vector_type(4))) float f32x4;    // MFMA accumulator

// ---- workspace layout (bytes) ----
// Anti-contention layout (R5, kept): barrier flags strided 1KB with 4 replicas
// 256B apart; h and r*h tile buffers replicated 4x.
#define CNT_OFF    0                          // barrier flags: 128 x 1KB (zeroed)
#define FLG_OFF    131072                     // 13 dtype flags
#define BS_OFF     135168                     // bias sums fp32: 3*1024*4
#define H64_OFF    147456                     // h bf16 u64[4 rep][32][256]: 256 KB (zeroed)
#define ZERO_BYTES (H64_OFF + 262144)
#define RH64_OFF   ZERO_BYTES                 // r*h u64[4 rep][32][256]: 256 KB (wbr)
#define XB_OFF     (1<<20)                    // x bf16: 8 MB
#define WB_OFF     (9<<20)                    // 6 weight mats bf16: 12 MB
#define WS_FULL    (21u<<20)
#define REP_STRIDE 8192                       // u64 per replica (64 KB)

// R13: dynamic LDS pad requested at launch (48 KB). Static LDS is ~53.7 KB;
// total ~102 KB > 80 KB forces at most ONE block per CU. This rules out the
// co-residency-straggler hypothesis: with all-to-all data dependence each
// round, any CU hosting 2 blocks would gate the whole grid every round.
// (R3's static-array pad probe was silently dead-store-eliminated by the
// compiler - LDS_Block_Size stayed 19 KB - so this was never actually tested.)
#define DYN_PAD_BYTES 49152

__device__ __forceinline__ float bf2f(u16 v) {
    unsigned u = ((unsigned)v) << 16;
    return __builtin_bit_cast(float, u);
}
__device__ __forceinline__ u16 f2bf(float f) {
    unsigned u = __builtin_bit_cast(unsigned, f);
    unsigned r = 0x7fffu + ((u >> 16) & 1u);   // RNE
    return (u16)((u + r) >> 16);
}
__device__ __forceinline__ float sigm(float x) { return 1.0f / (1.0f + __expf(-x)); }

__device__ __forceinline__ short8 cvt8f(const float* f) {
    short8 r;
#pragma unroll
    for (int j = 0; j < 8; j++) r[j] = (short)f2bf(f[j]);
    return r;
}
__device__ __forceinline__ short8 cvt8any(const void* src, long ei, unsigned isbf) {
    if (isbf) return *(const short8*)((const u16*)src + ei);
    return cvt8f((const float*)src + ei);
}

__device__ __forceinline__ u64 ld64(const u64* p) {
    return __hip_atomic_load(p, __ATOMIC_RELAXED, __HIP_MEMORY_SCOPE_AGENT);
}
__device__ __forceinline__ unsigned ld_flag(const unsigned* p) {
    return __hip_atomic_load(p, __ATOMIC_RELAXED, __HIP_MEMORY_SCOPE_AGENT);
}
__device__ __forceinline__ void st_flag(unsigned* p, unsigned v) {
    __hip_atomic_store(p, v, __ATOMIC_RELAXED, __HIP_MEMORY_SCOPE_AGENT);
}
__device__ __forceinline__ void st64(u64* p, u64 v) {
    __hip_atomic_store(p, v, __ATOMIC_RELAXED, __HIP_MEMORY_SCOPE_AGENT);
}

// ---- leaderless all-to-all grid barrier (R5/R7, byte-for-byte) ----
// Each block stores a MONOTONE epoch to 4 replica lines of its own 1KB-strided
// flag page; threads 0..NB-1 each poll one block's flag, reading replica
// (blk&3). Ordering: data moves via sc1 atomics (coherent at L3);
// __syncthreads drains vmcnt so all data stores are visible BEFORE the flag
// stores issue; consumer loads are also sc1 so they cannot hit stale L2.
// Flags zeroed once by memset; epochs 1..255 strictly increase per launch.
__device__ __forceinline__ void gbar(unsigned* flgs, unsigned e, unsigned nb) {
    __syncthreads();                 // drains vmcnt: all sc1 data stores at L3
    const unsigned tid = threadIdx.x;
    if (tid < 4)
        st_flag(flgs + blockIdx.x * 256 + tid * 64, e);   // 4 replicas, 256B apart
    if (tid < nb) {
        const unsigned* fp = flgs + tid * 256 + (blockIdx.x & 3) * 64;
        while (ld_flag(fp) < e)
            __builtin_amdgcn_s_sleep(1);
    }
    __syncthreads();
}

struct Ptrs { const void* p[13]; };

// dtype detector: bf16 u16s have exponent in [100,140] (or zero) ~100% for
// N(0,s) data; fp32 read as u16 passes ~58%.
__global__ __launch_bounds__(256) void detect_k(Ptrs ps, unsigned* flags) {
    const u16* a = (const u16*)ps.p[blockIdx.x];
    __shared__ int tot;
    if (threadIdx.x == 0) tot = 0;
    __syncthreads();
    int cnt = 0;
    for (int i = threadIdx.x; i < 1024; i += 256) {
        unsigned u = a[i];
        unsigned e = (u >> 7) & 0xFF;
        cnt += (e == 0 || (e >= 100 && e <= 140)) ? 1 : 0;
    }
    atomicAdd(&tot, cnt);
    __syncthreads();
    if (threadIdx.x == 0) flags[blockIdx.x] = (tot >= 920) ? 1u : 0u;
}

struct SPtrs { const void* x; const void* W[6]; const void* b[6]; };
// W order: Wz,Uz,Wr,Ur,Wh,Uh (flags 1,3,5,7,9,11); b pairs (bz,cz),(br,cr),(bh,ch).

__global__ __launch_bounds__(256) void stage_k(SPtrs ps, const unsigned* __restrict__ flags,
                                               u16* __restrict__ xb, u16* __restrict__ wb,
                                               float* __restrict__ bs, int do_x) {
    int blk = blockIdx.x, tid = threadIdx.x;
    int xblocks = do_x ? 2048 : 0;
    if (blk < xblocks) {                         // x: 4M elems
        long ei = ((long)blk * 256 + tid) * 8;
        *(short8*)(xb + ei) = cvt8any(ps.x, ei, flags[0]);
    } else if (blk < xblocks + 6 * 512) {        // weights: 1M elems each
        int r = (blk - xblocks) >> 9;
        const int fidx[6] = {1, 3, 5, 7, 9, 11};
        long ei = ((long)((blk - xblocks) & 511) * 256 + tid) * 8;
        *(short8*)(wb + (long)r * 1048576 + ei) = cvt8any(ps.W[r], ei, flags[fidx[r]]);
    } else {                                     // bias sums: bs[0]=z, [1]=r, [2]=h
        const int fb[3] = {2, 6, 10}, fc[3] = {4, 8, 12};
        for (int g = 0; g < 3; g++)
            for (int i = tid; i < 1024; i += 256) {
                float b = flags[fb[g]] ? bf2f(((const u16*)ps.b[2 * g])[i])
                                       : ((const float*)ps.b[2 * g])[i];
                float c = flags[fc[g]] ? bf2f(((const u16*)ps.b[2 * g + 1])[i])
                                       : ((const float*)ps.b[2 * g + 1])[i];
                bs[g * 1024 + i] = b + c;
            }
    }
}

// ---- persistent GRU: 128 blocks x 1024 thr (16 waves), K-split chains ----
// Block (ct=blk>>1, rt=blk&1) owns rows R=[16rt,+16) (batch), cols C=[16ct,+16).
// h and r*h live as u64[4 replicas][32][256] (4 bf16 per u64), accessed ONLY
// via sc1 atomics (L3 coherence point). Protocol + data path = R12 (best,
// 1239us): h AND rh cooperatively staged through LDS, 2 barriers/step,
// parallelized publisher epilogues.
// R13 change: +48KB dynamic LDS (launch arg) -> 1 block/CU guaranteed.
__global__ __launch_bounds__(1024, 4) void gru_rec(
    const void* __restrict__ xbase, int xmode,   // 1: xbase bf16-staged; 0: raw x
    const u16* __restrict__ wb, const float* __restrict__ bs,
    u64* __restrict__ h64, u64* __restrict__ rh64,
    const unsigned* __restrict__ flags,
    unsigned* __restrict__ flgs,
    void* __restrict__ out)
{
    extern __shared__ u64 dynpad[];              // R13: allocated via launch config

    const int tid  = threadIdx.x;
    const int lane = tid & 63, wave = tid >> 6;      // wave 0..15
    const int quad = lane >> 4, ln = lane & 15;
    const int blk  = blockIdx.x;
    const unsigned NB = gridDim.x;
    const int rep  = blk & 3;                        // data replica this block reads

    const unsigned xisbf = xmode ? 1u : flags[0];
    const unsigned outbf = flags[0];

    const int ct = blk >> 1, rt = blk & 1;
    const int R = rt * 16, C0 = ct * 16;

    // Phase A role: g = wave>>2 (0:hUr 1:xWr 2:hUz 3:xWz), kq = wave&3.
    const int gA  = wave >> 2, kqA = wave & 3;
    const int kb0 = kqA * 256;
    const int wmapA[4] = {3, 2, 1, 0};               // -> Ur, Wr, Uz, Wz
    const u16* BwA = wb + (long)wmapA[gA] * 1048576 + (C0 + ln) * 1024 + kb0 + quad * 8;
    const bool hA  = (gA == 0) || (gA == 2);
    const int hsc  = (kb0 >> 2) + quad * 2;          // hs u64 col base; iter i: +i*8
    const long xAo = ((long)(R + ln) * 128) * 1024 + kb0 + quad * 8; // + t*1024

    // Phase B role: gB = wave>>3 (0:rh@Uh 1:x@Wh), ke = wave&7.
    const int gB  = wave >> 3, keB = wave & 7;
    const int kb1 = keB * 128;
    const u16* BwB = wb + (long)(gB ? 4 : 5) * 1048576 + (C0 + ln) * 1024 + kb1 + quad * 8;
    const int rhsc = (kb1 >> 2) + quad * 2;          // hs u64 col base; iter i: +i*8
    const long xBo = ((long)(R + ln) * 128) * 1024 + kb1 + quad * 8; // + t*1024

    const float bias_z = bs[C0 + ln];
    const float bias_r = bs[1024 + C0 + ln];
    const float bias_h = bs[2048 + C0 + ln];

    __shared__ float sA[16][4][64];    // per-wave partials, conflict-free layout
    __shared__ float zt[4][64];        // z tile
    __shared__ float ht[2][4][64];     // h fp32 tile, parity dbuf (R12)
    __shared__ u16   tT[2][16][20];    // transpose staging, per publisher wave (R12)
    __shared__ __align__(16) u64 hs[16][258];  // staged h rows in phase A, then
                                               // REUSED for rh rows in phase B
                                               // (+2 pad, even stride: 16B align)

    if (wave == 0) {
#pragma unroll
        for (int r = 0; r < 4; r++) ht[0][r][lane] = 0.f;
        if (lane == 0) dynpad[0] = 0;            // touch the pad (kept live by launch)
    }
    __syncthreads();

    const int prow = lane >> 2, pseg = lane & 3;     // packer geometry

    // staging sources: wave w loads row R+w, lane l covers cols l, l+64, l+128, l+192
    const u64* hsrc  = h64  + rep * REP_STRIDE + (R + wave) * 256 + lane;
    const u64* rhsrc = rh64 + rep * REP_STRIDE + (R + wave) * 256 + lane;

    for (int t = 0; t < 128; t++) {
        const int par = t & 1;                       // ht[par] = h(t)
        { // ---- stage h rows into LDS (one sc1 read per word per block) ----
#pragma unroll
            for (int c = 0; c < 4; c++)
                hs[wave][lane + 64 * c] = ld64(hsrc + 64 * c);
        }
        __syncthreads();
        { // ---- phase A chains: 8 MFMAs ----
            f32x4 acc = (f32x4){0.f, 0.f, 0.f, 0.f};
            const long xo = xAo + (long)t * 1024;
#pragma unroll
            for (int i = 0; i < 8; i++) {
                short8 a = hA ? *(const short8*)&hs[ln][hsc + i * 8]
                              : cvt8any(xbase, xo + i * 32, xisbf);
                acc = __builtin_amdgcn_mfma_f32_16x16x32_bf16(
                    a, *(const short8*)(BwA + i * 32), acc, 0, 0, 0);
            }
#pragma unroll
            for (int r = 0; r < 4; r++) sA[wave][r][lane] = acc[r];
        }
        __syncthreads();
        // ---- mid-epilogue: waves 0 & 2 dup r-reduce, 2 replicas each ----
        if (wave == 0 || wave == 2) {
            const int cp = wave >> 1;                // tT copy / replica pair
#pragma unroll
            for (int r = 0; r < 4; r++) {
                float s = bias_r;
#pragma unroll
                for (int w = 0; w < 8; w++) s += sA[w][r][lane];
                float rv = sigm(s);
                tT[cp][quad * 4 + r][ln] = f2bf(rv * ht[par][r][lane]);
            }
            u64 v = (u64)tT[cp][prow][pseg * 4] | ((u64)tT[cp][prow][pseg * 4 + 1] << 16)
                  | ((u64)tT[cp][prow][pseg * 4 + 2] << 32)
                  | ((u64)tT[cp][prow][pseg * 4 + 3] << 48);
            u64* dst = &rh64[(R + prow) * 256 + ct * 4 + pseg];
            st64(dst + (2 * cp) * REP_STRIDE, v);
            st64(dst + (2 * cp + 1) * REP_STRIDE, v);
        } else if (wave == 1) { // z -> LDS
#pragma unroll
            for (int r = 0; r < 4; r++) {
                float s = bias_z;
#pragma unroll
                for (int w = 8; w < 16; w++) s += sA[w][r][lane];
                zt[r][lane] = sigm(s);
            }
        }
        gbar(flgs, 2 * t + 1, NB);
        { // ---- stage rh rows into LDS (all 16 waves, 4 loads each) ----
#pragma unroll
            for (int c = 0; c < 4; c++)
                hs[wave][lane + 64 * c] = ld64(rhsrc + 64 * c);
        }
        __syncthreads();
        { // ---- phase B chains: 4 MFMAs, operands from LDS ----
            f32x4 acc = (f32x4){0.f, 0.f, 0.f, 0.f};
            const long xo = xBo + (long)t * 1024;
#pragma unroll
            for (int i = 0; i < 4; i++) {
                short8 a = (gB == 0) ? *(const short8*)&hs[ln][rhsc + i * 8]
                                     : cvt8any(xbase, xo + i * 32, xisbf);
                acc = __builtin_amdgcn_mfma_f32_16x16x32_bf16(
                    a, *(const short8*)(BwB + i * 32), acc, 0, 0, 0);
            }
#pragma unroll
            for (int r = 0; r < 4; r++) sA[wave][r][lane] = acc[r];
        }
        __syncthreads();
        // ---- end-epilogue: waves 0,1,2 dup combine; split publish/out ----
        if (wave < 3) {
            float hnv[4];
#pragma unroll
            for (int r = 0; r < 4; r++) {
                float s = bias_h;
#pragma unroll
                for (int w = 0; w < 16; w++) s += sA[w][r][lane];
                float hh = sigm(s);
                float z  = zt[r][lane];
                float hv = ht[par][r][lane];
                hnv[r] = (1.0f - z) * hv + z * hh;
            }
            if (wave == 1) {          // output stores (off the publisher waves)
#pragma unroll
                for (int r = 0; r < 4; r++) {
                    int row = quad * 4 + r;
                    long oi = ((long)(t * 32) + R + row) * 1024 + C0 + ln; // ys (T,B,D)
                    if (outbf) ((u16*)out)[oi] = f2bf(hnv[r]);
                    else       ((float*)out)[oi] = hnv[r];
                }
            } else {                  // waves 0,2: publish 2 replicas each
                const int cp = wave >> 1;
#pragma unroll
                for (int r = 0; r < 4; r++) {
                    if (wave == 0) ht[par ^ 1][r][lane] = hnv[r];
                    tT[cp][quad * 4 + r][ln] = f2bf(hnv[r]);
                }
                u64 v = (u64)tT[cp][prow][pseg * 4] | ((u64)tT[cp][prow][pseg * 4 + 1] << 16)
                      | ((u64)tT[cp][prow][pseg * 4 + 2] << 32)
                      | ((u64)tT[cp][prow][pseg * 4 + 3] << 48);
                u64* dst = &h64[(R + prow) * 256 + ct * 4 + pseg];
                st64(dst + (2 * cp) * REP_STRIDE, v);
                st64(dst + (2 * cp + 1) * REP_STRIDE, v);
            }
        }
        if (t < 127) gbar(flgs, 2 * t + 2, NB);
    }
}

extern "C" void kernel_launch(void* const* d_in, const int* in_sizes, int n_in,
                              void* d_out, int out_size, void* d_ws, size_t ws_size,
                              hipStream_t stream)
{
    char* ws = (char*)d_ws;
    hipMemsetAsync(d_ws, 0, ZERO_BYTES, stream);   // barrier flags + dtypes + h64 reps

    unsigned* flgs  = (unsigned*)(ws + CNT_OFF);
    unsigned* flags = (unsigned*)(ws + FLG_OFF);
    float*    bs    = (float*)(ws + BS_OFF);
    u64*      h64   = (u64*)(ws + H64_OFF);
    u64*      rh64  = (u64*)(ws + RH64_OFF);
    u16*      xb    = (u16*)(ws + XB_OFF);

    Ptrs dp;
    for (int i = 0; i < 13; i++) dp.p[i] = d_in[i];
    detect_k<<<13, 256, 0, stream>>>(dp, flags);

    SPtrs sp;
    sp.x = d_in[0];
    sp.W[0] = d_in[1];  sp.W[1] = d_in[3];   // Wz, Uz
    sp.W[2] = d_in[5];  sp.W[3] = d_in[7];   // Wr, Ur
    sp.W[4] = d_in[9];  sp.W[5] = d_in[11];  // Wh, Uh
    sp.b[0] = d_in[2];  sp.b[1] = d_in[4];   // bz, cz
    sp.b[2] = d_in[6];  sp.b[3] = d_in[8];   // br, cr
    sp.b[4] = d_in[10]; sp.b[5] = d_in[12];  // bh, ch

    if (ws_size >= WS_FULL) {
        u16* wbuf = (u16*)(ws + WB_OFF);
        stage_k<<<2048 + 6 * 512 + 1, 256, 0, stream>>>(sp, flags, xb, wbuf, bs, 1);
        gru_rec<<<128, 1024, DYN_PAD_BYTES, stream>>>(xb, 1, wbuf, bs, h64, rh64, flags, flgs, d_out);
    } else {
        u16* wbuf = (u16*)(ws + XB_OFF);     // no x staging; weights at 1 MB
        stage_k<<<6 * 512 + 1, 256, 0, stream>>>(sp, flags, xb, wbuf, bs, 0);
        gru_rec<<<128, 1024, DYN_PAD_BYTES, stream>>>(d_in[0], 0, wbuf, bs, h64, rh64, flags, flgs, d_out);
    }
}

// Round 14
// 1342.724 us; speedup vs baseline: 1.0054x; 1.0054x over previous
//
#include <hip/hip_runtime.h>
#include <stdint.h>

// B=32, T=128, DIN=DOUT=1024. Input dtypes detected at runtime (bf16 vs fp32).
typedef unsigned short u16;
typedef unsigned long long u64;
typedef __attribute__((ext_vector_type(8))) short short8;   // 8 x bf16 MFMA operand
typedef __attribute__((ext_vector_type(4))) float f32x4;    // MFMA accumulator

// ---- workspace layout (bytes) ----
// Anti-contention layout (R5, kept): barrier flags strided 1KB with 4 replicas
// 256B apart; h and r*h tile buffers replicated 4x.
#define CNT_OFF    0                          // barrier flags: 128 x 1KB (zeroed)
#define FLG_OFF    131072                     // 13 dtype flags
#define BS_OFF     135168                     // bias sums fp32: 3*1024*4
#define H64_OFF    147456                     // h bf16 u64[4 rep][32][256]: 256 KB (zeroed)
#define ZERO_BYTES (H64_OFF + 262144)
#define RH64_OFF   ZERO_BYTES                 // r*h u64[4 rep][32][256]: 256 KB (wbr)
#define XB_OFF     (1<<20)                    // x bf16: 8 MB
#define WB_OFF     (9<<20)                    // 6 weight mats bf16: 12 MB
#define WS_FULL    (21u<<20)
#define REP_STRIDE 8192                       // u64 per replica (64 KB)

// FINAL (R14 = R12 revert): 13 experiments established this as the latency
// floor of the 2-exchange-per-step structure: 128 serial steps x 2 all-to-all
// L3-coherent visibility rounds (~4.8us/step), every pipe <2% utilized.
// Confirmed levers (applied): leaderless 1KB-strided replicated flags (R1/R5),
// LDS-staged h (R7) and rh (R11) cooperative sc1 reads, parallelized publisher
// epilogues (R12). Refuted: barrier algorithm (R2/R4/R10), clocks (R3),
// channel contention (R5), fewer blocks (R8), 16B asm loads (R9),
// co-residency (R13).

__device__ __forceinline__ float bf2f(u16 v) {
    unsigned u = ((unsigned)v) << 16;
    return __builtin_bit_cast(float, u);
}
__device__ __forceinline__ u16 f2bf(float f) {
    unsigned u = __builtin_bit_cast(unsigned, f);
    unsigned r = 0x7fffu + ((u >> 16) & 1u);   // RNE
    return (u16)((u + r) >> 16);
}
__device__ __forceinline__ float sigm(float x) { return 1.0f / (1.0f + __expf(-x)); }

__device__ __forceinline__ short8 cvt8f(const float* f) {
    short8 r;
#pragma unroll
    for (int j = 0; j < 8; j++) r[j] = (short)f2bf(f[j]);
    return r;
}
__device__ __forceinline__ short8 cvt8any(const void* src, long ei, unsigned isbf) {
    if (isbf) return *(const short8*)((const u16*)src + ei);
    return cvt8f((const float*)src + ei);
}

__device__ __forceinline__ u64 ld64(const u64* p) {
    return __hip_atomic_load(p, __ATOMIC_RELAXED, __HIP_MEMORY_SCOPE_AGENT);
}
__device__ __forceinline__ unsigned ld_flag(const unsigned* p) {
    return __hip_atomic_load(p, __ATOMIC_RELAXED, __HIP_MEMORY_SCOPE_AGENT);
}
__device__ __forceinline__ void st_flag(unsigned* p, unsigned v) {
    __hip_atomic_store(p, v, __ATOMIC_RELAXED, __HIP_MEMORY_SCOPE_AGENT);
}
__device__ __forceinline__ void st64(u64* p, u64 v) {
    __hip_atomic_store(p, v, __ATOMIC_RELAXED, __HIP_MEMORY_SCOPE_AGENT);
}

// ---- leaderless all-to-all grid barrier (R5/R7, byte-for-byte) ----
// Each block stores a MONOTONE epoch to 4 replica lines of its own 1KB-strided
// flag page; threads 0..NB-1 each poll one block's flag, reading replica
// (blk&3). Ordering: data moves via sc1 atomics (coherent at L3);
// __syncthreads drains vmcnt so all data stores are visible BEFORE the flag
// stores issue; consumer loads are also sc1 so they cannot hit stale L2.
// Flags zeroed once by memset; epochs 1..255 strictly increase per launch.
__device__ __forceinline__ void gbar(unsigned* flgs, unsigned e, unsigned nb) {
    __syncthreads();                 // drains vmcnt: all sc1 data stores at L3
    const unsigned tid = threadIdx.x;
    if (tid < 4)
        st_flag(flgs + blockIdx.x * 256 + tid * 64, e);   // 4 replicas, 256B apart
    if (tid < nb) {
        const unsigned* fp = flgs + tid * 256 + (blockIdx.x & 3) * 64;
        while (ld_flag(fp) < e)
            __builtin_amdgcn_s_sleep(1);
    }
    __syncthreads();
}

struct Ptrs { const void* p[13]; };

// dtype detector: bf16 u16s have exponent in [100,140] (or zero) ~100% for
// N(0,s) data; fp32 read as u16 passes ~58%.
__global__ __launch_bounds__(256) void detect_k(Ptrs ps, unsigned* flags) {
    const u16* a = (const u16*)ps.p[blockIdx.x];
    __shared__ int tot;
    if (threadIdx.x == 0) tot = 0;
    __syncthreads();
    int cnt = 0;
    for (int i = threadIdx.x; i < 1024; i += 256) {
        unsigned u = a[i];
        unsigned e = (u >> 7) & 0xFF;
        cnt += (e == 0 || (e >= 100 && e <= 140)) ? 1 : 0;
    }
    atomicAdd(&tot, cnt);
    __syncthreads();
    if (threadIdx.x == 0) flags[blockIdx.x] = (tot >= 920) ? 1u : 0u;
}

struct SPtrs { const void* x; const void* W[6]; const void* b[6]; };
// W order: Wz,Uz,Wr,Ur,Wh,Uh (flags 1,3,5,7,9,11); b pairs (bz,cz),(br,cr),(bh,ch).

__global__ __launch_bounds__(256) void stage_k(SPtrs ps, const unsigned* __restrict__ flags,
                                               u16* __restrict__ xb, u16* __restrict__ wb,
                                               float* __restrict__ bs, int do_x) {
    int blk = blockIdx.x, tid = threadIdx.x;
    int xblocks = do_x ? 2048 : 0;
    if (blk < xblocks) {                         // x: 4M elems
        long ei = ((long)blk * 256 + tid) * 8;
        *(short8*)(xb + ei) = cvt8any(ps.x, ei, flags[0]);
    } else if (blk < xblocks + 6 * 512) {        // weights: 1M elems each
        int r = (blk - xblocks) >> 9;
        const int fidx[6] = {1, 3, 5, 7, 9, 11};
        long ei = ((long)((blk - xblocks) & 511) * 256 + tid) * 8;
        *(short8*)(wb + (long)r * 1048576 + ei) = cvt8any(ps.W[r], ei, flags[fidx[r]]);
    } else {                                     // bias sums: bs[0]=z, [1]=r, [2]=h
        const int fb[3] = {2, 6, 10}, fc[3] = {4, 8, 12};
        for (int g = 0; g < 3; g++)
            for (int i = tid; i < 1024; i += 256) {
                float b = flags[fb[g]] ? bf2f(((const u16*)ps.b[2 * g])[i])
                                       : ((const float*)ps.b[2 * g])[i];
                float c = flags[fc[g]] ? bf2f(((const u16*)ps.b[2 * g + 1])[i])
                                       : ((const float*)ps.b[2 * g + 1])[i];
                bs[g * 1024 + i] = b + c;
            }
    }
}

// ---- persistent GRU: 128 blocks x 1024 thr (16 waves), K-split chains ----
// Block (ct=blk>>1, rt=blk&1) owns rows R=[16rt,+16) (batch), cols C=[16ct,+16).
// h and r*h live as u64[4 replicas][32][256] (4 bf16 per u64), accessed ONLY
// via sc1 atomics (L3 coherence point). h AND rh cooperatively staged through
// LDS (16 waves x 4 loads), 2 barriers/step, parallelized publisher epilogues.
__global__ __launch_bounds__(1024, 4) void gru_rec(
    const void* __restrict__ xbase, int xmode,   // 1: xbase bf16-staged; 0: raw x
    const u16* __restrict__ wb, const float* __restrict__ bs,
    u64* __restrict__ h64, u64* __restrict__ rh64,
    const unsigned* __restrict__ flags,
    unsigned* __restrict__ flgs,
    void* __restrict__ out)
{
    const int tid  = threadIdx.x;
    const int lane = tid & 63, wave = tid >> 6;      // wave 0..15
    const int quad = lane >> 4, ln = lane & 15;
    const int blk  = blockIdx.x;
    const unsigned NB = gridDim.x;
    const int rep  = blk & 3;                        // data replica this block reads

    const unsigned xisbf = xmode ? 1u : flags[0];
    const unsigned outbf = flags[0];

    const int ct = blk >> 1, rt = blk & 1;
    const int R = rt * 16, C0 = ct * 16;

    // Phase A role: g = wave>>2 (0:hUr 1:xWr 2:hUz 3:xWz), kq = wave&3.
    const int gA  = wave >> 2, kqA = wave & 3;
    const int kb0 = kqA * 256;
    const int wmapA[4] = {3, 2, 1, 0};               // -> Ur, Wr, Uz, Wz
    const u16* BwA = wb + (long)wmapA[gA] * 1048576 + (C0 + ln) * 1024 + kb0 + quad * 8;
    const bool hA  = (gA == 0) || (gA == 2);
    const int hsc  = (kb0 >> 2) + quad * 2;          // hs u64 col base; iter i: +i*8
    const long xAo = ((long)(R + ln) * 128) * 1024 + kb0 + quad * 8; // + t*1024

    // Phase B role: gB = wave>>3 (0:rh@Uh 1:x@Wh), ke = wave&7.
    const int gB  = wave >> 3, keB = wave & 7;
    const int kb1 = keB * 128;
    const u16* BwB = wb + (long)(gB ? 4 : 5) * 1048576 + (C0 + ln) * 1024 + kb1 + quad * 8;
    const int rhsc = (kb1 >> 2) + quad * 2;          // hs u64 col base; iter i: +i*8
    const long xBo = ((long)(R + ln) * 128) * 1024 + kb1 + quad * 8; // + t*1024

    const float bias_z = bs[C0 + ln];
    const float bias_r = bs[1024 + C0 + ln];
    const float bias_h = bs[2048 + C0 + ln];

    __shared__ float sA[16][4][64];    // per-wave partials, conflict-free layout
    __shared__ float zt[4][64];        // z tile
    __shared__ float ht[2][4][64];     // h fp32 tile, parity dbuf (R12)
    __shared__ u16   tT[2][16][20];    // transpose staging, per publisher wave (R12)
    __shared__ __align__(16) u64 hs[16][258];  // staged h rows in phase A, then
                                               // REUSED for rh rows in phase B
                                               // (+2 pad, even stride: 16B align)

    if (wave == 0)
#pragma unroll
        for (int r = 0; r < 4; r++) ht[0][r][lane] = 0.f;
    __syncthreads();

    const int prow = lane >> 2, pseg = lane & 3;     // packer geometry

    // staging sources: wave w loads row R+w, lane l covers cols l, l+64, l+128, l+192
    const u64* hsrc  = h64  + rep * REP_STRIDE + (R + wave) * 256 + lane;
    const u64* rhsrc = rh64 + rep * REP_STRIDE + (R + wave) * 256 + lane;

    for (int t = 0; t < 128; t++) {
        const int par = t & 1;                       // ht[par] = h(t)
        { // ---- stage h rows into LDS (one sc1 read per word per block) ----
#pragma unroll
            for (int c = 0; c < 4; c++)
                hs[wave][lane + 64 * c] = ld64(hsrc + 64 * c);
        }
        __syncthreads();
        { // ---- phase A chains: 8 MFMAs ----
            f32x4 acc = (f32x4){0.f, 0.f, 0.f, 0.f};
            const long xo = xAo + (long)t * 1024;
#pragma unroll
            for (int i = 0; i < 8; i++) {
                short8 a = hA ? *(const short8*)&hs[ln][hsc + i * 8]
                              : cvt8any(xbase, xo + i * 32, xisbf);
                acc = __builtin_amdgcn_mfma_f32_16x16x32_bf16(
                    a, *(const short8*)(BwA + i * 32), acc, 0, 0, 0);
            }
#pragma unroll
            for (int r = 0; r < 4; r++) sA[wave][r][lane] = acc[r];
        }
        __syncthreads();
        // ---- mid-epilogue: waves 0 & 2 dup r-reduce, 2 replicas each ----
        if (wave == 0 || wave == 2) {
            const int cp = wave >> 1;                // tT copy / replica pair
#pragma unroll
            for (int r = 0; r < 4; r++) {
                float s = bias_r;
#pragma unroll
                for (int w = 0; w < 8; w++) s += sA[w][r][lane];
                float rv = sigm(s);
                tT[cp][quad * 4 + r][ln] = f2bf(rv * ht[par][r][lane]);
            }
            u64 v = (u64)tT[cp][prow][pseg * 4] | ((u64)tT[cp][prow][pseg * 4 + 1] << 16)
                  | ((u64)tT[cp][prow][pseg * 4 + 2] << 32)
                  | ((u64)tT[cp][prow][pseg * 4 + 3] << 48);
            u64* dst = &rh64[(R + prow) * 256 + ct * 4 + pseg];
            st64(dst + (2 * cp) * REP_STRIDE, v);
            st64(dst + (2 * cp + 1) * REP_STRIDE, v);
        } else if (wave == 1) { // z -> LDS
#pragma unroll
            for (int r = 0; r < 4; r++) {
                float s = bias_z;
#pragma unroll
                for (int w = 8; w < 16; w++) s += sA[w][r][lane];
                zt[r][lane] = sigm(s);
            }
        }
        gbar(flgs, 2 * t + 1, NB);
        { // ---- stage rh rows into LDS (all 16 waves, 4 loads each) ----
#pragma unroll
            for (int c = 0; c < 4; c++)
                hs[wave][lane + 64 * c] = ld64(rhsrc + 64 * c);
        }
        __syncthreads();
        { // ---- phase B chains: 4 MFMAs, operands from LDS ----
            f32x4 acc = (f32x4){0.f, 0.f, 0.f, 0.f};
            const long xo = xBo + (long)t * 1024;
#pragma unroll
            for (int i = 0; i < 4; i++) {
                short8 a = (gB == 0) ? *(const short8*)&hs[ln][rhsc + i * 8]
                                     : cvt8any(xbase, xo + i * 32, xisbf);
                acc = __builtin_amdgcn_mfma_f32_16x16x32_bf16(
                    a, *(const short8*)(BwB + i * 32), acc, 0, 0, 0);
            }
#pragma unroll
            for (int r = 0; r < 4; r++) sA[wave][r][lane] = acc[r];
        }
        __syncthreads();
        // ---- end-epilogue: waves 0,1,2 dup combine; split publish/out ----
        if (wave < 3) {
            float hnv[4];
#pragma unroll
            for (int r = 0; r < 4; r++) {
                float s = bias_h;
#pragma unroll
                for (int w = 0; w < 16; w++) s += sA[w][r][lane];
                float hh = sigm(s);
                float z  = zt[r][lane];
                float hv = ht[par][r][lane];
                hnv[r] = (1.0f - z) * hv + z * hh;
            }
            if (wave == 1) {          // output stores (off the publisher waves)
#pragma unroll
                for (int r = 0; r < 4; r++) {
                    int row = quad * 4 + r;
                    long oi = ((long)(t * 32) + R + row) * 1024 + C0 + ln; // ys (T,B,D)
                    if (outbf) ((u16*)out)[oi] = f2bf(hnv[r]);
                    else       ((float*)out)[oi] = hnv[r];
                }
            } else {                  // waves 0,2: publish 2 replicas each
                const int cp = wave >> 1;
#pragma unroll
                for (int r = 0; r < 4; r++) {
                    if (wave == 0) ht[par ^ 1][r][lane] = hnv[r];
                    tT[cp][quad * 4 + r][ln] = f2bf(hnv[r]);
                }
                u64 v = (u64)tT[cp][prow][pseg * 4] | ((u64)tT[cp][prow][pseg * 4 + 1] << 16)
                      | ((u64)tT[cp][prow][pseg * 4 + 2] << 32)
                      | ((u64)tT[cp][prow][pseg * 4 + 3] << 48);
                u64* dst = &h64[(R + prow) * 256 + ct * 4 + pseg];
                st64(dst + (2 * cp) * REP_STRIDE, v);
                st64(dst + (2 * cp + 1) * REP_STRIDE, v);
            }
        }
        if (t < 127) gbar(flgs, 2 * t + 2, NB);
    }
}

extern "C" void kernel_launch(void* const* d_in, const int* in_sizes, int n_in,
                              void* d_out, int out_size, void* d_ws, size_t ws_size,
                              hipStream_t stream)
{
    char* ws = (char*)d_ws;
    hipMemsetAsync(d_ws, 0, ZERO_BYTES, stream);   // barrier flags + dtypes + h64 reps

    unsigned* flgs  = (unsigned*)(ws + CNT_OFF);
    unsigned* flags = (unsigned*)(ws + FLG_OFF);
    float*    bs    = (float*)(ws + BS_OFF);
    u64*      h64   = (u64*)(ws + H64_OFF);
    u64*      rh64  = (u64*)(ws + RH64_OFF);
    u16*      xb    = (u16*)(ws + XB_OFF);

    Ptrs dp;
    for (int i = 0; i < 13; i++) dp.p[i] = d_in[i];
    detect_k<<<13, 256, 0, stream>>>(dp, flags);

    SPtrs sp;
    sp.x = d_in[0];
    sp.W[0] = d_in[1];  sp.W[1] = d_in[3];   // Wz, Uz
    sp.W[2] = d_in[5];  sp.W[3] = d_in[7];   // Wr, Ur
    sp.W[4] = d_in[9];  sp.W[5] = d_in[11];  // Wh, Uh
    sp.b[0] = d_in[2];  sp.b[1] = d_in[4];   // bz, cz
    sp.b[2] = d_in[6];  sp.b[3] = d_in[8];   // br, cr
    sp.b[4] = d_in[10]; sp.b[5] = d_in[12];  // bh, ch

    if (ws_size >= WS_FULL) {
        u16* wbuf = (u16*)(ws + WB_OFF);
        stage_k<<<2048 + 6 * 512 + 1, 256, 0, stream>>>(sp, flags, xb, wbuf, bs, 1);
        gru_rec<<<128, 1024, 0, stream>>>(xb, 1, wbuf, bs, h64, rh64, flags, flgs, d_out);
    } else {
        u16* wbuf = (u16*)(ws + XB_OFF);     // no x staging; weights at 1 MB
        stage_k<<<6 * 512 + 1, 256, 0, stream>>>(sp, flags, xb, wbuf, bs, 0);
        gru_rec<<<128, 1024, 0, stream>>>(d_in[0], 0, wbuf, bs, h64, rh64, flags, flgs, d_out);
    }
}